// Round 1
// baseline (702.522 us; speedup 1.0000x reference)
//
#include <hip/hip_runtime.h>
#include <hip/hip_bf16.h>

// SNN forward: conv1 -> LIF -> conv2 -> LIF -> conv3 -> LIF -> (mean over T ∘ FC)
// Key identity: mean over T commutes with FC, so only spike COUNTS per (b,c,m)
// are needed after LIF3.
//
// Layout for spike/membrane buffers: float[B][C][129][64], data at m+12,
// zero padding elsewhere (removes all W bounds checks in the big convs).

#define NB 32
#define NC 64
#define NT 129
#define TIN 128
#define NM 40
#define MP 64
#define PADL 12

static __device__ __forceinline__ float lif_tau_div(float x) {
    const float TAU = 10.0f / 7.0f;   // fp32(10/7), IEEE divide below
    return x / TAU;
}

// ---- transpose conv weights [co][ci][4][3] -> [tap=kh*3+kw][ci][co] ----
__global__ void prep_wT(const float* __restrict__ w, float* __restrict__ wT) {
    int idx = blockIdx.x * 256 + threadIdx.x;      // 12*64*64 = 49152
    if (idx >= 12 * 64 * 64) return;
    int co = idx & 63;
    int ci = (idx >> 6) & 63;
    int tap = idx >> 12;                            // 0..11
    wT[idx] = w[(co * 64 + ci) * 12 + tap];
}

// ---- conv1 (1->64ch, 4x3, pad(2,1)) fused with LIF1; writes padded spikes ----
__global__ void conv1_lif1(const float* __restrict__ x, const float* __restrict__ w1,
                           float* __restrict__ out) {
    int c = blockIdx.x & 63;
    int b = blockIdx.x >> 6;
    int m = threadIdx.x;                 // 0..63 (padded coordinate)
    int mm = m - PADL;                   // data coordinate
    bool active = ((unsigned)mm < (unsigned)NM);

    float* orow = out + ((size_t)(b * NC + c) * NT) * MP + m;

    float w[4][3];
#pragma unroll
    for (int kh = 0; kh < 4; kh++)
#pragma unroll
        for (int kw = 0; kw < 3; kw++) w[kh][kw] = w1[(c * 4 + kh) * 3 + kw];

    const float* xb = x + (size_t)b * TIN * NM;

    // sliding window: xw[r] holds input row (t-2+r)
    float xw[4][3];
#pragma unroll
    for (int r = 0; r < 4; r++)
#pragma unroll
        for (int j = 0; j < 3; j++) xw[r][j] = 0.0f;
#pragma unroll
    for (int r = 2; r < 4; r++) {
        int row = r - 2;                 // rows 0,1
#pragma unroll
        for (int j = 0; j < 3; j++) {
            int mc = mm - 1 + j;
            xw[r][j] = (active && (unsigned)mc < (unsigned)NM) ? xb[row * NM + mc] : 0.0f;
        }
    }

    float v = 0.0f;
    for (int t = 0; t < NT; t++) {
        float u = 0.0f;
#pragma unroll
        for (int r = 0; r < 4; r++)
#pragma unroll
            for (int j = 0; j < 3; j++) u += xw[r][j] * w[r][j];

        v = v + lif_tau_div(u - v);
        float s = (v >= 1.0f) ? 1.0f : 0.0f;
        orow[(size_t)t * MP] = active ? s : 0.0f;
        v = (v >= 1.0f) ? 0.0f : v;      // hard reset == v*(1-s)

        // shift window, load row t+2 (needed by iteration t+1)
#pragma unroll
        for (int r = 0; r < 3; r++)
#pragma unroll
            for (int j = 0; j < 3; j++) xw[r][j] = xw[r + 1][j];
        int nrow = t + 2;
#pragma unroll
        for (int j = 0; j < 3; j++) {
            int mc = mm - 1 + j;
            xw[3][j] = (active && nrow < TIN && (unsigned)mc < (unsigned)NM)
                           ? xb[nrow * NM + mc] : 0.0f;
        }
    }
}

// ---- big dilated 64->64ch conv (4x3). block=(t,b); 256 thr = 64 co-lanes x 4 m-waves ----
template <int PAD_H, int DIL_H, int PAD_W, int DIL_W>
__global__ __launch_bounds__(256) void convK(const float* __restrict__ sin,
                                             const float* __restrict__ wT,
                                             float* __restrict__ uout) {
    constexpr int SLEN = 10 + 2 * DIL_W;       // 16 (layer2) / 28 (layer3)
    int t = blockIdx.x;
    int b = blockIdx.y;
    int lane = threadIdx.x & 63;               // co
    int wv = threadIdx.x >> 6;                 // 0..3
    int m0 = __builtin_amdgcn_readfirstlane(wv * 10);

    float acc[10];
#pragma unroll
    for (int j = 0; j < 10; j++) acc[j] = 0.0f;

    const float* sbase = sin + (size_t)b * NC * NT * MP;

#pragma unroll
    for (int kh = 0; kh < 4; kh++) {
        int row = t - PAD_H + DIL_H * kh;
        if ((unsigned)row < (unsigned)NT) {
            for (int ci = 0; ci < NC; ci++) {
                // wave-uniform address -> scalar loads (spikes broadcast to all co lanes)
                const float* sp = sbase + ((size_t)(ci * NT + row) * MP + (PADL - PAD_W) + m0);
                float sseg[SLEN];
#pragma unroll
                for (int i = 0; i < SLEN; i++) sseg[i] = sp[i];
#pragma unroll
                for (int kw = 0; kw < 3; kw++) {
                    float wval = wT[((kh * 3 + kw) * 64 + ci) * 64 + lane];
#pragma unroll
                    for (int j = 0; j < 10; j++) acc[j] += sseg[j + DIL_W * kw] * wval;
                }
            }
        }
    }

    // transpose through LDS for coalesced (and pad-zeroing) stores
    __shared__ float tile[64][41];
#pragma unroll
    for (int j = 0; j < 10; j++) tile[lane][m0 + j] = acc[j];
    __syncthreads();

#pragma unroll
    for (int r = 0; r < 16; r++) {
        int idx = threadIdx.x + r * 256;       // 0..4095 = co*64 + mpad
        int co = idx >> 6;
        int mpad = idx & 63;
        int dm = mpad - PADL;
        float val = ((unsigned)dm < (unsigned)NM) ? tile[co][dm] : 0.0f;
        uout[((size_t)(b * NC + co) * NT + t) * MP + mpad] = val;
    }
}

// ---- LIF over T, in place (membrane potentials -> spikes), data region only ----
__global__ void lif_inplace(float* __restrict__ buf) {
    int tid = blockIdx.x * 256 + threadIdx.x;  // 32*64*40
    if (tid >= NB * NC * NM) return;
    int m = tid % NM;
    int bc = tid / NM;
    float* p = buf + (size_t)bc * NT * MP + PADL + m;
    float v = 0.0f;
    for (int t = 0; t < NT; t++) {
        float u = p[(size_t)t * MP];
        v = v + lif_tau_div(u - v);
        float s = (v >= 1.0f) ? 1.0f : 0.0f;
        p[(size_t)t * MP] = s;
        v = (v >= 1.0f) ? 0.0f : v;
    }
}

// ---- LIF3: only spike counts survive (mean commutes with FC) ----
__global__ void lif_sum(const float* __restrict__ buf, float* __restrict__ hsum) {
    int tid = blockIdx.x * 256 + threadIdx.x;  // 32*64*40
    if (tid >= NB * NC * NM) return;
    int m = tid % NM;
    int bc = tid / NM;
    const float* p = buf + (size_t)bc * NT * MP + PADL + m;
    float v = 0.0f;
    float cnt = 0.0f;
    for (int t = 0; t < NT; t++) {
        float u = p[(size_t)t * MP];
        v = v + lif_tau_div(u - v);
        if (v >= 1.0f) { cnt += 1.0f; v = 0.0f; }
    }
    hsum[tid] = cnt;                            // index == b*2560 + c*40 + m == b,cm
}

// ---- FC on spike counts: y[b,k] = bf[k] + (sum_cm cnt*wf[k,cm]) / 129 ----
__global__ void fc_out(const float* __restrict__ hsum, const float* __restrict__ wf,
                       const float* __restrict__ bfv, float* __restrict__ out) {
    int b = blockIdx.x;
    int tid = threadIdx.x;                      // 256
    float p[12];
#pragma unroll
    for (int k = 0; k < 12; k++) p[k] = 0.0f;
    for (int cm = tid; cm < NC * NM; cm += 256) {
        float h = hsum[b * NC * NM + cm];
#pragma unroll
        for (int k = 0; k < 12; k++) p[k] += h * wf[k * (NC * NM) + cm];
    }
    __shared__ float red[12][4];
    int lane = tid & 63, w = tid >> 6;
#pragma unroll
    for (int k = 0; k < 12; k++) {
        float s = p[k];
#pragma unroll
        for (int off = 32; off > 0; off >>= 1) s += __shfl_down(s, off, 64);
        if (lane == 0) red[k][w] = s;
    }
    __syncthreads();
    if (tid < 12) {
        float s = red[tid][0] + red[tid][1] + red[tid][2] + red[tid][3];
        out[b * 12 + tid] = bfv[tid] + s / 129.0f;
    }
}

extern "C" void kernel_launch(void* const* d_in, const int* in_sizes, int n_in,
                              void* d_out, int out_size, void* d_ws, size_t ws_size,
                              hipStream_t stream) {
    const float* x  = (const float*)d_in[0];
    const float* w1 = (const float*)d_in[1];
    const float* w2 = (const float*)d_in[2];
    const float* w3 = (const float*)d_in[3];
    const float* wf = (const float*)d_in[4];
    const float* bf = (const float*)d_in[5];
    float* out = (float*)d_out;

    const size_t BUF = (size_t)NB * NC * NT * MP;   // 16,908,288 floats (67.6 MB)
    float* bufA = (float*)d_ws;
    float* bufB = bufA + BUF;
    float* wT2  = bufB + BUF;
    float* wT3  = wT2 + 12 * 64 * 64;
    float* hsum = wT3 + 12 * 64 * 64;               // total ~136 MB of d_ws

    prep_wT<<<192, 256, 0, stream>>>(w2, wT2);
    prep_wT<<<192, 256, 0, stream>>>(w3, wT3);

    conv1_lif1<<<NB * NC, 64, 0, stream>>>(x, w1, bufA);          // -> spikes1 (bufA)

    convK<6, 4, 3, 3><<<dim3(NT, NB), 256, 0, stream>>>(bufA, wT2, bufB);   // -> u2
    lif_inplace<<<(NB * NC * NM) / 256, 256, 0, stream>>>(bufB);            // -> spikes2

    convK<24, 16, 9, 9><<<dim3(NT, NB), 256, 0, stream>>>(bufB, wT3, bufA); // -> u3
    lif_sum<<<(NB * NC * NM) / 256, 256, 0, stream>>>(bufA, hsum);          // -> counts

    fc_out<<<NB, 256, 0, stream>>>(hsum, wf, bf, out);
}

// Round 2
// 374.683 us; speedup vs baseline: 1.8750x; 1.8750x over previous
//
#include <hip/hip_runtime.h>
#include <hip/hip_bf16.h>
#include <string.h>

// SNN forward. Big convs on MFMA f16 (spikes {0,1} exact in f16; fp32 weights
// split w = hi + lo/2048 across two f16 MFMA accumulations).
//
// Spike buffers: _Float16 [B][TP=192][MPAD=64][CI=64], data at t+24, m+12.
// Zero padding (memset) removes ALL bounds checks in the MFMA conv.
// u buffer: fp32 [B][129][40][64] (membrane potentials, compact).

typedef __attribute__((ext_vector_type(8))) _Float16 v8h;
typedef __attribute__((ext_vector_type(16))) float v16f;
typedef _Float16 half_t;

#define NB 32
#define NC 64
#define NT 129
#define TIN 128
#define NM 40
#define TP 192
#define TOFF 24
#define MPAD 64
#define MOFF 12
#define ROWB 8192        // bytes per (b,t) spike row = 64*64*2
#define LROW 8704        // LDS spike row stride = 64*136
#define MSTR 136         // LDS m' stride (128 + 8 pad: kills bank conflicts)
#define WLDS 104448      // LDS weight region offset = 12*LROW
#define LDSSZ 153600     // 104448 + 48*1024

// ---- expand conv weights into exact MFMA A-fragment layout ----
// wf flat: [cq(4)][tap(12)][ct(2)][hl(2)][lane(64)] x 16B.
// A-frag (32x32x16 f16): lane holds A[co = ct*32 + (lane&31)][ci = cq*16 + (lane>>5)*8 + jj]
__global__ void prep_wfrag(const float* __restrict__ w, uint4* __restrict__ wf) {
    int tid = blockIdx.x * 256 + threadIdx.x;   // 12288
    if (tid >= 12288) return;
    int lane = tid & 63;
    int rest = tid >> 6;
    int hl = rest & 1;
    int ct = (rest >> 1) & 1;
    int tap = (rest >> 2) % 12;
    int cq = (rest >> 2) / 12;
    int kh = tap / 3, kw = tap % 3;
    int co = ct * 32 + (lane & 31);
    unsigned short o[8];
#pragma unroll
    for (int jj = 0; jj < 8; jj++) {
        int ci = cq * 16 + (lane >> 5) * 8 + jj;
        float wv = w[((co * 64 + ci) * 4 + kh) * 3 + kw];
        _Float16 hi = (_Float16)wv;
        _Float16 val = hl ? (_Float16)((wv - (float)hi) * 2048.0f) : hi;
        unsigned short us;
        __builtin_memcpy(&us, &val, 2);
        o[jj] = us;
    }
    uint4 r;
    __builtin_memcpy(&r, o, 16);
    wf[tid] = r;
}

// ---- conv1 (1->64ch, 4x3, pad(2,1)) fused with LIF1 -> f16 spikes ----
__global__ void conv1_lif1(const float* __restrict__ x, const float* __restrict__ w1,
                           half_t* __restrict__ s1) {
    const int m = blockIdx.x;        // 0..39
    const int b = blockIdx.y;
    const int c = threadIdx.x;       // 0..63 (lane = output channel)
    float w[4][3];
#pragma unroll
    for (int kh = 0; kh < 4; kh++)
#pragma unroll
        for (int kw = 0; kw < 3; kw++) w[kh][kw] = w1[(c * 4 + kh) * 3 + kw];
    const float* xb = x + (size_t)b * TIN * NM;
    float xw[4][3];                  // window rows t-2..t+1 (block-uniform)
#pragma unroll
    for (int rr = 0; rr < 4; rr++)
#pragma unroll
        for (int kw = 0; kw < 3; kw++) xw[rr][kw] = 0.f;
#pragma unroll
    for (int rr = 2; rr < 4; rr++) {
#pragma unroll
        for (int kw = 0; kw < 3; kw++) {
            int mc = m - 1 + kw;
            xw[rr][kw] = ((unsigned)mc < (unsigned)NM) ? xb[(rr - 2) * NM + mc] : 0.f;
        }
    }
    half_t* orow = s1 + ((size_t)(b * TP + TOFF) * MPAD + m + MOFF) * 64 + c;
    float v = 0.f;
    const float TAUc = 10.0f / 7.0f;
    for (int t = 0; t < NT; t++) {
        float uacc = 0.f;
#pragma unroll
        for (int kh = 0; kh < 4; kh++)
#pragma unroll
            for (int kw = 0; kw < 3; kw++) uacc += xw[kh][kw] * w[kh][kw];
        v = v + (uacc - v) / TAUc;
        float s = (v >= 1.0f) ? 1.0f : 0.0f;
        orow[(size_t)t * MPAD * 64] = (half_t)s;
        if (v >= 1.0f) v = 0.0f;
#pragma unroll
        for (int rr = 0; rr < 3; rr++)
#pragma unroll
            for (int kw = 0; kw < 3; kw++) xw[rr][kw] = xw[rr + 1][kw];
        int nrow = t + 2;
#pragma unroll
        for (int kw = 0; kw < 3; kw++) {
            int mc = m - 1 + kw;
            xw[3][kw] = (nrow < TIN && (unsigned)mc < (unsigned)NM) ? xb[nrow * NM + mc] : 0.f;
        }
    }
}

// ---- MFMA conv: 64->64ch, 4x3 dilated. Block owns (b, t = r mod DIL lattice, 9 outputs).
// 512 thr = 8 waves; wave w owns pos-tiles {2w, 2w+1} (tile = 2 j x 16 m), both co-tiles.
template <int DH, int PH, int DW, int PW, int RMOD>
__global__ __launch_bounds__(512, 2) void convM(const half_t* __restrict__ spk,
                                                const uint4* __restrict__ wfrag,
                                                float* __restrict__ u) {
    extern __shared__ char lds[];
    const int tid = threadIdx.x;
    const int lane = tid & 63;
    const int wv = tid >> 6;                    // 0..7
    const int r = blockIdx.x % RMOD;
    const int q = blockIdx.x / RMOD;
    const int b = blockIdx.y;
    const int j0 = 8 * q;

    // ---- stage 12 spike rows (96 KB) with 136B m-stride ----
    const char* srcb = (const char*)spk + (size_t)b * TP * ROWB;
#pragma unroll
    for (int k = 0; k < 12; k++) {
        int chunk = wv * 12 + k;                // 0..95 (1KB chunks)
        int i = chunk >> 3;                     // LDS row 0..11
        int s8 = chunk & 7;
        int row = r + DH * (j0 + i) + (TOFF - PH);   // always in [0,192)
        uint4 val = *((const uint4*)(srcb + (size_t)row * ROWB + s8 * 1024) + lane);
        *(uint4*)(lds + i * LROW + (s8 * 8 + (lane >> 3)) * MSTR + (lane & 7) * 16) = val;
    }

    // per-lane pos decode
    const int pos = lane & 31;
    const int jlocal = pos >> 4;
    const int mloc = pos & 15;
    const int hseg = lane >> 5;

    int baseB[2];
#pragma unroll
    for (int pt = 0; pt < 2; pt++) {
        int tau = 2 * wv + pt;                  // 0..15 (15 = dummy)
        int jp = tau / 3, mc = tau % 3;
        int j = 2 * jp + jlocal;
        int jeff = j > 8 ? 8 : j;               // clamp: dummy lanes read valid LDS
        int m = mc * 16 + mloc;
        int meff = m > 39 ? 39 : m;
        baseB[pt] = jeff * LROW + (meff + MOFF - PW) * MSTR + hseg * 16;
    }

    v16f acc[2][2][2];                          // [pos-tile][co-tile][hi/lo]
#pragma unroll
    for (int a = 0; a < 2; a++)
#pragma unroll
        for (int c = 0; c < 2; c++)
#pragma unroll
            for (int h = 0; h < 2; h++) acc[a][c][h] = (v16f)(0.0f);

    for (int cq = 0; cq < 4; cq++) {            // ci-quarters of 16
        __syncthreads();
        // stage 48 KB of weight fragments for this ci-quarter
#pragma unroll
        for (int k = 0; k < 6; k++) {
            int chunk = wv * 6 + k;             // == tap*4 + ct*2 + hl
            uint4 val = *(wfrag + (size_t)(cq * 48 + chunk) * 64 + lane);
            *(uint4*)(lds + WLDS + chunk * 1024 + lane * 16) = val;
        }
        __syncthreads();
        const int cqoff = cq * 32;
#pragma unroll
        for (int tap = 0; tap < 12; tap++) {
            const int kh = tap / 3, kw = tap % 3;
            const int bofs = kh * LROW + kw * (DW * MSTR) + cqoff;
            v8h B0 = *(const v8h*)(lds + baseB[0] + bofs);
            v8h B1 = *(const v8h*)(lds + baseB[1] + bofs);
            const int wbase = WLDS + tap * 4096 + lane * 16;
            v8h A00 = *(const v8h*)(lds + wbase);
            v8h A01 = *(const v8h*)(lds + wbase + 1024);
            v8h A10 = *(const v8h*)(lds + wbase + 2048);
            v8h A11 = *(const v8h*)(lds + wbase + 3072);
            acc[0][0][0] = __builtin_amdgcn_mfma_f32_32x32x16_f16(A00, B0, acc[0][0][0], 0, 0, 0);
            acc[0][0][1] = __builtin_amdgcn_mfma_f32_32x32x16_f16(A01, B0, acc[0][0][1], 0, 0, 0);
            acc[0][1][0] = __builtin_amdgcn_mfma_f32_32x32x16_f16(A10, B0, acc[0][1][0], 0, 0, 0);
            acc[0][1][1] = __builtin_amdgcn_mfma_f32_32x32x16_f16(A11, B0, acc[0][1][1], 0, 0, 0);
            acc[1][0][0] = __builtin_amdgcn_mfma_f32_32x32x16_f16(A00, B1, acc[1][0][0], 0, 0, 0);
            acc[1][0][1] = __builtin_amdgcn_mfma_f32_32x32x16_f16(A01, B1, acc[1][0][1], 0, 0, 0);
            acc[1][1][0] = __builtin_amdgcn_mfma_f32_32x32x16_f16(A10, B1, acc[1][1][0], 0, 0, 0);
            acc[1][1][1] = __builtin_amdgcn_mfma_f32_32x32x16_f16(A11, B1, acc[1][1][1], 0, 0, 0);
        }
    }

    // ---- epilogue: u = hi + lo/2048, masked float4 stores ----
    const float invs = 1.0f / 2048.0f;
#pragma unroll
    for (int pt = 0; pt < 2; pt++) {
        int tau = 2 * wv + pt;
        int jp = tau / 3, mc = tau % 3;
        int j = 2 * jp + jlocal;
        int t = r + DH * (j0 + j);
        int m = mc * 16 + mloc;
        if (j <= 8 && t < NT && m < NM) {
            float* base = u + ((size_t)(b * NT + t) * NM + m) * 64;
#pragma unroll
            for (int ct = 0; ct < 2; ct++) {
#pragma unroll
                for (int g = 0; g < 4; g++) {
                    int co = ct * 32 + 8 * g + 4 * hseg;   // D row = (reg&3)+8*(reg>>2)+4*(lane>>5)
                    float4 val;
                    val.x = acc[pt][ct][0][4 * g + 0] + acc[pt][ct][1][4 * g + 0] * invs;
                    val.y = acc[pt][ct][0][4 * g + 1] + acc[pt][ct][1][4 * g + 1] * invs;
                    val.z = acc[pt][ct][0][4 * g + 2] + acc[pt][ct][1][4 * g + 2] * invs;
                    val.w = acc[pt][ct][0][4 * g + 3] + acc[pt][ct][1][4 * g + 3] * invs;
                    *(float4*)(base + co) = val;
                }
            }
        }
    }
}

// ---- LIF over T: u (fp32) -> f16 spikes into padded layout ----
__global__ void lif_spikes(const float* __restrict__ u, half_t* __restrict__ s2) {
    int tid = blockIdx.x * 256 + threadIdx.x;   // 81920 = 32*40*64
    int b = tid / 2560;
    int rem = tid % 2560;
    int m = rem >> 6;
    int co = rem & 63;
    const float* up = u + ((size_t)b * NT * NM + m) * 64 + co;
    half_t* sp = s2 + ((size_t)(b * TP + TOFF) * MPAD + m + MOFF) * 64 + co;
    float v = 0.f;
    const float TAUc = 10.0f / 7.0f;
    for (int t = 0; t < NT; t++) {
        float uu = up[(size_t)t * NM * 64];
        v = v + (uu - v) / TAUc;
        float s = (v >= 1.0f) ? 1.0f : 0.0f;
        sp[(size_t)t * MPAD * 64] = (half_t)s;
        if (v >= 1.0f) v = 0.f;
    }
}

// ---- LIF3: spike counts only (mean commutes with FC) ----
__global__ void lif_sum(const float* __restrict__ u, float* __restrict__ hsum) {
    int tid = blockIdx.x * 256 + threadIdx.x;   // 81920
    int b = tid / 2560;
    int rem = tid % 2560;
    int m = rem >> 6;
    int co = rem & 63;
    const float* up = u + ((size_t)b * NT * NM + m) * 64 + co;
    float v = 0.f, cnt = 0.f;
    const float TAUc = 10.0f / 7.0f;
    for (int t = 0; t < NT; t++) {
        float uu = up[(size_t)t * NM * 64];
        v = v + (uu - v) / TAUc;
        if (v >= 1.0f) { cnt += 1.0f; v = 0.f; }
    }
    hsum[b * 2560 + co * NM + m] = cnt;         // feature index = c*40 + m
}

// ---- FC on counts: y[b,k] = bf[k] + (sum_cm cnt*wf[k,cm]) / 129 ----
__global__ void fc_out(const float* __restrict__ hsum, const float* __restrict__ wf,
                       const float* __restrict__ bfv, float* __restrict__ out) {
    int b = blockIdx.x;
    int tid = threadIdx.x;
    float p[12];
#pragma unroll
    for (int k = 0; k < 12; k++) p[k] = 0.0f;
    for (int cm = tid; cm < NC * NM; cm += 256) {
        float h = hsum[b * NC * NM + cm];
#pragma unroll
        for (int k = 0; k < 12; k++) p[k] += h * wf[k * (NC * NM) + cm];
    }
    __shared__ float red[12][4];
    int lane = tid & 63, w = tid >> 6;
#pragma unroll
    for (int k = 0; k < 12; k++) {
        float s = p[k];
#pragma unroll
        for (int off = 32; off > 0; off >>= 1) s += __shfl_down(s, off, 64);
        if (lane == 0) red[k][w] = s;
    }
    __syncthreads();
    if (tid < 12) {
        float s = red[tid][0] + red[tid][1] + red[tid][2] + red[tid][3];
        out[b * 12 + tid] = bfv[tid] + s / 129.0f;
    }
}

extern "C" void kernel_launch(void* const* d_in, const int* in_sizes, int n_in,
                              void* d_out, int out_size, void* d_ws, size_t ws_size,
                              hipStream_t stream) {
    const float* x  = (const float*)d_in[0];
    const float* w1 = (const float*)d_in[1];
    const float* w2 = (const float*)d_in[2];
    const float* w3 = (const float*)d_in[3];
    const float* wf = (const float*)d_in[4];
    const float* bf = (const float*)d_in[5];
    float* out = (float*)d_out;

    char* ws = (char*)d_ws;
    half_t* s1  = (half_t*)ws;                      // 50,331,648 B
    half_t* s2  = (half_t*)(ws + 50331648);         // 50,331,648 B
    float*  u   = (float*)(ws + 100663296);         // 42,270,720 B
    uint4*  wf2 = (uint4*)(ws + 142934016);         // 196,608 B
    uint4*  wf3 = (uint4*)(ws + 143130624);         // 196,608 B
    float* hsum = (float*)(ws + 143327232);         // 327,680 B  (end ~143.7 MB)

    // allow >64KB dynamic LDS (no-op if already allowed)
    static bool attr_set = false;
    if (!attr_set) {
        hipFuncSetAttribute((const void*)&convM<4, 6, 3, 3, 4>,
                            hipFuncAttributeMaxDynamicSharedMemorySize, LDSSZ);
        hipFuncSetAttribute((const void*)&convM<16, 24, 9, 9, 16>,
                            hipFuncAttributeMaxDynamicSharedMemorySize, LDSSZ);
        attr_set = true;
    }

    hipMemsetAsync(s1, 0, 50331648, stream);        // zero padding regions
    hipMemsetAsync(s2, 0, 50331648, stream);

    prep_wfrag<<<48, 256, 0, stream>>>(w2, wf2);
    prep_wfrag<<<48, 256, 0, stream>>>(w3, wf3);

    conv1_lif1<<<dim3(40, 32), 64, 0, stream>>>(x, w1, s1);

    convM<4, 6, 3, 3, 4><<<dim3(16, 32), 512, LDSSZ, stream>>>(s1, wf2, u);
    lif_spikes<<<320, 256, 0, stream>>>(u, s2);

    convM<16, 24, 9, 9, 16><<<dim3(16, 32), 512, LDSSZ, stream>>>(s2, wf3, u);
    lif_sum<<<320, 256, 0, stream>>>(u, hsum);

    fc_out<<<32, 256, 0, stream>>>(hsum, wf, bf, out);
}

// Round 3
// 363.035 us; speedup vs baseline: 1.9351x; 1.0321x over previous
//
#include <hip/hip_runtime.h>

// SNN forward, round 3.
// conv2/conv3 on MFMA f16 (spikes {0,1} exact; w = hi + lo/2048 split).
// Spike buffers COMPACT: _Float16 [B][129][40][64(ci)] (no pads, no memsets;
// convM staging zero-fills out-of-range rows/cols into LDS).
// u buffer: fp32 [B][129][40][64].
// convM: 256 thr, 1 barrier, spikes-only LDS (44/55 KB -> 2-3 blocks/CU),
// weights streamed from global ([tap][cq] sequential, L1/L2-resident).

typedef __attribute__((ext_vector_type(8))) _Float16 v8h;
typedef __attribute__((ext_vector_type(16))) float v16f;
typedef _Float16 half_t;

#define NB 32
#define NC 64
#define NT 129
#define TIN 128
#define NM 40
#define MSTR 136          // LDS per-m stride (128 data + 8): conflict-free, 8B-aligned
#define SROWB 5120        // global spike row bytes = 40*64*2

// ---- weights -> MFMA A-fragments, order [tap12][cq4][ct2][hl2][lane64]x16B ----
// A-frag (32x32x16 f16): lane holds A[co=ct*32+(lane&31)][ci=cq*16+(lane>>5)*8+jj]
__global__ void prep_wfrag(const float* __restrict__ w, uint4* __restrict__ wf) {
    int tid = blockIdx.x * 256 + threadIdx.x;   // 12288
    if (tid >= 12288) return;
    int lane = tid & 63;
    int rest = tid >> 6;                        // = frag_id = tap*16+cq*4+ct*2+hl
    int hl = rest & 1;
    int ct = (rest >> 1) & 1;
    int cq = (rest >> 2) & 3;
    int tap = rest >> 4;
    int kh = tap / 3, kw = tap % 3;
    int co = ct * 32 + (lane & 31);
    unsigned short o[8];
#pragma unroll
    for (int jj = 0; jj < 8; jj++) {
        int ci = cq * 16 + (lane >> 5) * 8 + jj;
        float wv = w[((co * 64 + ci) * 4 + kh) * 3 + kw];
        _Float16 hi = (_Float16)wv;
        _Float16 val = hl ? (_Float16)((wv - (float)hi) * 2048.0f) : hi;
        unsigned short us;
        __builtin_memcpy(&us, &val, 2);
        o[jj] = us;
    }
    uint4 r;
    __builtin_memcpy(&r, o, 16);
    wf[tid] = r;
}

// ---- conv1 (1->64ch, 4x3, pad(2,1)) fused with LIF1 -> compact f16 spikes ----
__global__ void conv1_lif1(const float* __restrict__ x, const float* __restrict__ w1,
                           half_t* __restrict__ s1) {
    const int mg = blockIdx.x;        // 0..9
    const int b = blockIdx.y;
    const int c = threadIdx.x & 63;
    const int ml = threadIdx.x >> 6;  // 0..3
    const int m = mg * 4 + ml;
    float w[4][3];
#pragma unroll
    for (int kh = 0; kh < 4; kh++)
#pragma unroll
        for (int kw = 0; kw < 3; kw++) w[kh][kw] = w1[(c * 4 + kh) * 3 + kw];
    const float* xb = x + (size_t)b * TIN * NM;
    float xw[4][3];
#pragma unroll
    for (int rr = 0; rr < 4; rr++)
#pragma unroll
        for (int kw = 0; kw < 3; kw++) xw[rr][kw] = 0.f;
#pragma unroll
    for (int rr = 2; rr < 4; rr++)
#pragma unroll
        for (int kw = 0; kw < 3; kw++) {
            int mc = m - 1 + kw;
            xw[rr][kw] = ((unsigned)mc < (unsigned)NM) ? xb[(rr - 2) * NM + mc] : 0.f;
        }
    half_t* orow = s1 + ((size_t)b * NT * NM + m) * 64 + c;
    float v = 0.f;
    const float TAUc = 10.0f / 7.0f;
    for (int t = 0; t < NT; t++) {
        float uacc = 0.f;
#pragma unroll
        for (int kh = 0; kh < 4; kh++)
#pragma unroll
            for (int kw = 0; kw < 3; kw++) uacc += xw[kh][kw] * w[kh][kw];
        v = v + (uacc - v) / TAUc;
        float s = (v >= 1.0f) ? 1.0f : 0.0f;
        orow[(size_t)t * NM * 64] = (half_t)s;
        if (v >= 1.0f) v = 0.0f;
#pragma unroll
        for (int rr = 0; rr < 3; rr++)
#pragma unroll
            for (int kw = 0; kw < 3; kw++) xw[rr][kw] = xw[rr + 1][kw];
        int nrow = t + 2;
#pragma unroll
        for (int kw = 0; kw < 3; kw++) {
            int mc = m - 1 + kw;
            xw[3][kw] = (nrow < TIN && (unsigned)mc < (unsigned)NM) ? xb[nrow * NM + mc] : 0.f;
        }
    }
}

// ---- MFMA conv 64->64, 4x3 dilated. Block: (b, r-lattice, jspan=4, all m, all co).
// 256 thr = 4 waves x 2 pos-tiles(2j x 16m). One barrier. Weights from global.
template <int DH, int PH, int DW, int PW, int EXT, int RSH>
__global__ __launch_bounds__(256, 2) void convM(const half_t* __restrict__ spk,
                                                const uint4* __restrict__ wfrag,
                                                float* __restrict__ u) {
    extern __shared__ char lds[];
    constexpr int LROWB = EXT * MSTR;
    constexpr int NCH = 7 * EXT * 8;            // 16B chunks staged
    const int tid = threadIdx.x;
    const int lane = tid & 63;
    const int wv = tid >> 6;                    // 0..3
    const int bx = blockIdx.x;                  // 0..32
    const int b = blockIdx.y;
    int r, q;
    if (bx < 32) { r = bx & ((1 << RSH) - 1); q = bx >> RSH; }
    else         { r = 0; q = 32 >> RSH; }
    const int j0 = 4 * q;

    // ---- stage 7 spike rows (zero-fill OOB), then ONE barrier ----
    const char* spb = (const char*)spk + (size_t)b * NT * SROWB;
#pragma unroll
    for (int k = 0; k < (NCH + 255) / 256; k++) {
        int c = tid + k * 256;
        if (c < NCH) {
            int i = c / (EXT * 8);
            int rem = c - i * (EXT * 8);
            int s = rem >> 3;
            int ci8 = rem & 7;
            int tg = r - PH + DH * (j0 + i);
            int md = s - PW;
            uint4 val = make_uint4(0u, 0u, 0u, 0u);
            if ((unsigned)tg < (unsigned)NT && (unsigned)md < (unsigned)NM)
                val = *(const uint4*)(spb + ((size_t)tg * NM + md) * 128 + ci8 * 16);
            *(uint4*)(lds + i * LROWB + s * MSTR + ci8 * 16) = val;
        }
    }
    __syncthreads();

    // ---- per-lane pos decode: tile = (2j x 16m); 6 real tiles on 8 slots ----
    const int pos = lane & 31;
    const int jlocal = pos >> 4;
    const int mloc = pos & 15;
    const int hseg = lane >> 5;

    int baseB[2], jj[2], mm[2], tt[2];
    bool tvalid[2];
#pragma unroll
    for (int pt = 0; pt < 2; pt++) {
        int tau = 2 * wv + pt;                  // 0..7 (6,7 dummy)
        tvalid[pt] = (tau <= 5);
        int tauc = tvalid[pt] ? tau : 5;
        int jp = tauc / 3;
        int mc = tauc - 3 * jp;
        int j = 2 * jp + jlocal;                // 0..3
        int m = mc * 16 + mloc;                 // 0..47
        int meff = m > 39 ? 39 : m;
        jj[pt] = j; mm[pt] = m;
        tt[pt] = r + DH * (j0 + j);
        baseB[pt] = j * LROWB + meff * MSTR + hseg * 16;
    }

    v16f acc[2][2][2];                          // [pos-tile][co-tile][hi/lo]
#pragma unroll
    for (int a = 0; a < 2; a++)
#pragma unroll
        for (int c = 0; c < 2; c++)
#pragma unroll
            for (int h = 0; h < 2; h++) acc[a][c][h] = (v16f)(0.0f);

    const uint4* wp = wfrag + lane;             // sequential A stream
#pragma unroll
    for (int tap = 0; tap < 12; tap++) {
        const int kh = tap / 3, kw = tap % 3;
        const int bo = kh * LROWB + kw * (DW * MSTR);
#pragma unroll
        for (int cq = 0; cq < 4; cq++) {
            v8h B0 = *(const v8h*)(lds + baseB[0] + bo + cq * 32);
            v8h B1 = *(const v8h*)(lds + baseB[1] + bo + cq * 32);
            const uint4* wq = wp + (tap * 4 + cq) * 256;
            v8h A00 = *(const v8h*)(wq);
            v8h A01 = *(const v8h*)(wq + 64);
            v8h A10 = *(const v8h*)(wq + 128);
            v8h A11 = *(const v8h*)(wq + 192);
            acc[0][0][0] = __builtin_amdgcn_mfma_f32_32x32x16_f16(A00, B0, acc[0][0][0], 0, 0, 0);
            acc[0][0][1] = __builtin_amdgcn_mfma_f32_32x32x16_f16(A01, B0, acc[0][0][1], 0, 0, 0);
            acc[0][1][0] = __builtin_amdgcn_mfma_f32_32x32x16_f16(A10, B0, acc[0][1][0], 0, 0, 0);
            acc[0][1][1] = __builtin_amdgcn_mfma_f32_32x32x16_f16(A11, B0, acc[0][1][1], 0, 0, 0);
            acc[1][0][0] = __builtin_amdgcn_mfma_f32_32x32x16_f16(A00, B1, acc[1][0][0], 0, 0, 0);
            acc[1][0][1] = __builtin_amdgcn_mfma_f32_32x32x16_f16(A01, B1, acc[1][0][1], 0, 0, 0);
            acc[1][1][0] = __builtin_amdgcn_mfma_f32_32x32x16_f16(A10, B1, acc[1][1][0], 0, 0, 0);
            acc[1][1][1] = __builtin_amdgcn_mfma_f32_32x32x16_f16(A11, B1, acc[1][1][1], 0, 0, 0);
        }
    }

    // ---- epilogue: u = hi + lo/2048 ----
    const float invs = 1.0f / 2048.0f;
#pragma unroll
    for (int pt = 0; pt < 2; pt++) {
        if (tvalid[pt] && mm[pt] < NM && tt[pt] < NT) {
            float* base = u + ((size_t)(b * NT + tt[pt]) * NM + mm[pt]) * 64;
#pragma unroll
            for (int ct = 0; ct < 2; ct++) {
#pragma unroll
                for (int g = 0; g < 4; g++) {
                    int co = ct * 32 + 8 * g + 4 * hseg;  // D row = (reg&3)+8*(reg>>2)+4*(lane>>5)
                    float4 val;
                    val.x = acc[pt][ct][0][4 * g + 0] + acc[pt][ct][1][4 * g + 0] * invs;
                    val.y = acc[pt][ct][0][4 * g + 1] + acc[pt][ct][1][4 * g + 1] * invs;
                    val.z = acc[pt][ct][0][4 * g + 2] + acc[pt][ct][1][4 * g + 2] * invs;
                    val.w = acc[pt][ct][0][4 * g + 3] + acc[pt][ct][1][4 * g + 3] * invs;
                    *(float4*)(base + co) = val;
                }
            }
        }
    }
}

// ---- LIF over T: u fp32 -> compact f16 spikes ----
__global__ void lif_spikes(const float* __restrict__ u, half_t* __restrict__ s2) {
    int tid = blockIdx.x * 256 + threadIdx.x;   // 81920
    int b = tid / 2560;
    int rem = tid % 2560;
    int m = rem >> 6;
    int co = rem & 63;
    const float* up = u + ((size_t)b * NT * NM + m) * 64 + co;
    half_t* sp = s2 + ((size_t)b * NT * NM + m) * 64 + co;
    float v = 0.f;
    const float TAUc = 10.0f / 7.0f;
    for (int t = 0; t < NT; t++) {
        float uu = up[(size_t)t * NM * 64];
        v = v + (uu - v) / TAUc;
        float s = (v >= 1.0f) ? 1.0f : 0.0f;
        sp[(size_t)t * NM * 64] = (half_t)s;
        if (v >= 1.0f) v = 0.f;
    }
}

// ---- LIF3: spike counts only (mean commutes with FC) ----
__global__ void lif_sum(const float* __restrict__ u, float* __restrict__ hsum) {
    int tid = blockIdx.x * 256 + threadIdx.x;   // 81920
    int b = tid / 2560;
    int rem = tid % 2560;
    int m = rem >> 6;
    int co = rem & 63;
    const float* up = u + ((size_t)b * NT * NM + m) * 64 + co;
    float v = 0.f, cnt = 0.f;
    const float TAUc = 10.0f / 7.0f;
    for (int t = 0; t < NT; t++) {
        float uu = up[(size_t)t * NM * 64];
        v = v + (uu - v) / TAUc;
        if (v >= 1.0f) { cnt += 1.0f; v = 0.f; }
    }
    hsum[b * 2560 + co * NM + m] = cnt;         // feature index = c*40 + m
}

// ---- FC on counts: y[b,k] = bf[k] + (sum_cm cnt*wf[k,cm]) / 129 ----
__global__ void fc_out(const float* __restrict__ hsum, const float* __restrict__ wf,
                       const float* __restrict__ bfv, float* __restrict__ out) {
    int b = blockIdx.x;
    int tid = threadIdx.x;
    float p[12];
#pragma unroll
    for (int k = 0; k < 12; k++) p[k] = 0.0f;
    for (int cm = tid; cm < NC * NM; cm += 256) {
        float h = hsum[b * NC * NM + cm];
#pragma unroll
        for (int k = 0; k < 12; k++) p[k] += h * wf[k * (NC * NM) + cm];
    }
    __shared__ float red[12][4];
    int lane = tid & 63, w = tid >> 6;
#pragma unroll
    for (int k = 0; k < 12; k++) {
        float s = p[k];
#pragma unroll
        for (int off = 32; off > 0; off >>= 1) s += __shfl_down(s, off, 64);
        if (lane == 0) red[k][w] = s;
    }
    __syncthreads();
    if (tid < 12) {
        float s = red[tid][0] + red[tid][1] + red[tid][2] + red[tid][3];
        out[b * 12 + tid] = bfv[tid] + s / 129.0f;
    }
}

extern "C" void kernel_launch(void* const* d_in, const int* in_sizes, int n_in,
                              void* d_out, int out_size, void* d_ws, size_t ws_size,
                              hipStream_t stream) {
    const float* x  = (const float*)d_in[0];
    const float* w1 = (const float*)d_in[1];
    const float* w2 = (const float*)d_in[2];
    const float* w3 = (const float*)d_in[3];
    const float* wf = (const float*)d_in[4];
    const float* bf = (const float*)d_in[5];
    float* out = (float*)d_out;

    char* ws = (char*)d_ws;
    half_t* s1  = (half_t*)ws;                      // 21,135,360 B
    half_t* s2  = (half_t*)(ws + 21135360);         // 21,135,360 B
    float*  u   = (float*)(ws + 42270720);          // 42,270,720 B
    uint4*  wf2 = (uint4*)(ws + 84541440);          // 196,608 B
    uint4*  wf3 = (uint4*)(ws + 84738048);          // 196,608 B
    float* hsum = (float*)(ws + 84934656);          // 327,680 B (end ~85.3 MB)

    prep_wfrag<<<48, 256, 0, stream>>>(w2, wf2);
    prep_wfrag<<<48, 256, 0, stream>>>(w3, wf3);

    conv1_lif1<<<dim3(10, 32), 256, 0, stream>>>(x, w1, s1);

    // layer 2: DH=4 PH=6 DW=3 PW=3, EXT=46, r in [0,4): LDS = 7*46*136 = 43792 B
    convM<4, 6, 3, 3, 46, 2><<<dim3(33, 32), 256, 43792, stream>>>(s1, wf2, u);
    lif_spikes<<<320, 256, 0, stream>>>(u, s2);

    // layer 3: DH=16 PH=24 DW=9 PW=9, EXT=58, r in [0,16): LDS = 7*58*136 = 55216 B
    convM<16, 24, 9, 9, 58, 4><<<dim3(33, 32), 256, 55216, stream>>>(s2, wf3, u);
    lif_sum<<<320, 256, 0, stream>>>(u, hsum);

    fc_out<<<32, 256, 0, stream>>>(hsum, wf, bf, out);
}

// Round 4
// 280.260 us; speedup vs baseline: 2.5067x; 1.2954x over previous
//
#include <hip/hip_runtime.h>

// SNN forward, round 4.
// convW: weight-stream MFMA conv, 3 pos-tiles/wave (12 accs), 1 wave/SIMD,
// deep compiler prefetch; per (tap,cq): 4 global A-frags + 3 LDS B-frags + 12 MFMA.
// LIF kernels: unroll-8 batched loads (one latency per 8 steps).
// Numerics: accumulation order per output identical to round 3 (bit-identical u).

typedef __attribute__((ext_vector_type(8))) _Float16 v8h;
typedef __attribute__((ext_vector_type(16))) float v16f;
typedef _Float16 half_t;

#define NB 32
#define NC 64
#define NT 129
#define TIN 128
#define NM 40
#define MSTR 144          // LDS per-slot stride: 16B-aligned, conflict-free
#define SROWB 5120        // global spike row bytes = 40*64*2

// ---- weights -> MFMA A-fragments, order [tap12][cq4][ct2][hl2][lane64]x16B ----
// A-frag (32x32x16 f16): lane holds A[co=ct*32+(lane&31)][ci=cq*16+(lane>>5)*8+jj]
__global__ void prep_wfrag(const float* __restrict__ w, uint4* __restrict__ wf) {
    int tid = blockIdx.x * 256 + threadIdx.x;   // 12288
    if (tid >= 12288) return;
    int lane = tid & 63;
    int rest = tid >> 6;
    int hl = rest & 1;
    int ct = (rest >> 1) & 1;
    int cq = (rest >> 2) & 3;
    int tap = rest >> 4;
    int kh = tap / 3, kw = tap % 3;
    int co = ct * 32 + (lane & 31);
    unsigned short o[8];
#pragma unroll
    for (int jj = 0; jj < 8; jj++) {
        int ci = cq * 16 + (lane >> 5) * 8 + jj;
        float wv = w[((co * 64 + ci) * 4 + kh) * 3 + kw];
        _Float16 hi = (_Float16)wv;
        _Float16 val = hl ? (_Float16)((wv - (float)hi) * 2048.0f) : hi;
        unsigned short us;
        __builtin_memcpy(&us, &val, 2);
        o[jj] = us;
    }
    uint4 r;
    __builtin_memcpy(&r, o, 16);
    wf[tid] = r;
}

// ---- conv1 (1->64ch, 4x3, pad(2,1)) + LIF1, unroll-8 row prefetch ----
__global__ void conv1_lif1(const float* __restrict__ x, const float* __restrict__ w1,
                           half_t* __restrict__ s1) {
    const int mg = blockIdx.x;        // 0..9
    const int b = blockIdx.y;
    const int c = threadIdx.x & 63;
    const int ml = threadIdx.x >> 6;  // 0..3
    const int m = mg * 4 + ml;
    float w[4][3];
#pragma unroll
    for (int kh = 0; kh < 4; kh++)
#pragma unroll
        for (int kw = 0; kw < 3; kw++) w[kh][kw] = w1[(c * 4 + kh) * 3 + kw];
    const float* xb = x + (size_t)b * TIN * NM;

    float xw[12][3];                  // rows tb-2 .. tb+9
#pragma unroll
    for (int rr = 0; rr < 12; rr++)
#pragma unroll
        for (int kw = 0; kw < 3; kw++) xw[rr][kw] = 0.f;
#pragma unroll
    for (int rr = 2; rr < 4; rr++)
#pragma unroll
        for (int kw = 0; kw < 3; kw++) {
            int mc = m - 1 + kw;
            xw[rr][kw] = ((unsigned)mc < (unsigned)NM) ? xb[(rr - 2) * NM + mc] : 0.f;
        }

    half_t* orow = s1 + ((size_t)b * NT * NM + m) * 64 + c;
    float v = 0.f;
    const float TAUc = 10.0f / 7.0f;

    for (int tb = 0; tb < NT; tb += 8) {
        // batch-load rows tb+2 .. tb+9 (independent of the recurrence)
#pragma unroll
        for (int q = 0; q < 8; q++) {
            int row = tb + 2 + q;
#pragma unroll
            for (int kw = 0; kw < 3; kw++) {
                int mc = m - 1 + kw;
                xw[4 + q][kw] = (row < TIN && (unsigned)mc < (unsigned)NM)
                                    ? xb[row * NM + mc] : 0.f;
            }
        }
        int kmax = (NT - tb) < 8 ? (NT - tb) : 8;
#pragma unroll
        for (int k = 0; k < 8; k++) {
            if (k < kmax) {
                float uacc = 0.f;
#pragma unroll
                for (int kh = 0; kh < 4; kh++)
#pragma unroll
                    for (int kw = 0; kw < 3; kw++) uacc += xw[k + kh][kw] * w[kh][kw];
                v = v + (uacc - v) / TAUc;
                float s = (v >= 1.0f) ? 1.0f : 0.0f;
                orow[(size_t)(tb + k) * NM * 64] = (half_t)s;
                if (v >= 1.0f) v = 0.0f;
            }
        }
#pragma unroll
        for (int rr = 0; rr < 4; rr++)
#pragma unroll
            for (int kw = 0; kw < 3; kw++) xw[rr][kw] = xw[8 + rr][kw];
    }
}

// ---- MFMA conv 64->64, 4x3 dilated, weight-streaming.
// grid (17, B). bx<16: r = bx%RMOD, jj0 = (bx/RMOD)*8; bx==16: r=0, jj0=(16/RMOD)*8.
// 256 thr = 4 waves; wave w owns jj-pair (jj0+2w, jj0+2w+1) x 3 m-tiles {0,16,24}.
template <int DH, int PH, int DW, int PW, int EXT, int RMOD>
__global__ __launch_bounds__(256, 1) void convW(const half_t* __restrict__ spk,
                                                const uint4* __restrict__ wfrag,
                                                float* __restrict__ u) {
    extern __shared__ char lds[];
    constexpr int LROWB = EXT * MSTR;
    constexpr int NCH = 11 * EXT * 8;           // 16B staging chunks
    const int tid = threadIdx.x;
    const int lane = tid & 63;
    const int wv = tid >> 6;                    // 0..3
    const int bx = blockIdx.x;
    const int b = blockIdx.y;
    int r, jj0;
    if (bx < 16) { r = bx % RMOD; jj0 = (bx / RMOD) * 8; }
    else         { r = 0;         jj0 = (16 / RMOD) * 8; }

    // ---- stage 11 lattice rows (zero-fill OOB), one barrier ----
    const char* spb = (const char*)spk + (size_t)b * NT * SROWB;
#pragma unroll
    for (int k = 0; k < (NCH + 255) / 256; k++) {
        int c = tid + k * 256;
        if (c < NCH) {
            int i = c / (EXT * 8);
            int rem = c - i * (EXT * 8);
            int s = rem >> 3;
            int ci8 = rem & 7;
            int tg = r - PH + DH * (jj0 + i);
            int md = s - PW;
            uint4 val = make_uint4(0u, 0u, 0u, 0u);
            if ((unsigned)tg < (unsigned)NT && (unsigned)md < (unsigned)NM)
                val = *(const uint4*)(spb + ((size_t)tg * NM + md) * 128 + ci8 * 16);
            *(uint4*)(lds + i * LROWB + s * MSTR + ci8 * 16) = val;
        }
    }
    __syncthreads();

    // ---- lane decode: pos-tile = 2jj x 16m ----
    const int pos = lane & 31;
    const int jl = pos >> 4;
    const int ml = pos & 15;
    const int hseg = lane >> 5;
    const int jj = jj0 + 2 * wv + jl;
    const int ldsrow = 2 * wv + jl;             // 0..7
    const int t = r + DH * jj;
    const int mtb[3] = {0, 16, 24};

    int baseB[3];
#pragma unroll
    for (int mt = 0; mt < 3; mt++)
        baseB[mt] = ldsrow * LROWB + (mtb[mt] + ml) * MSTR + hseg * 16;

    v16f acc[3][2][2];                          // [m-tile][co-tile][hi/lo]
#pragma unroll
    for (int a = 0; a < 3; a++)
#pragma unroll
        for (int c = 0; c < 2; c++)
#pragma unroll
            for (int h = 0; h < 2; h++) acc[a][c][h] = (v16f)(0.0f);

    const uint4* wp = wfrag + lane;
#pragma unroll
    for (int tap = 0; tap < 12; tap++) {
        const int kh = tap / 3, kw = tap % 3;
        const int bo = kh * LROWB + kw * (DW * MSTR);
#pragma unroll
        for (int cq = 0; cq < 4; cq++) {
            v8h B0 = *(const v8h*)(lds + baseB[0] + bo + cq * 32);
            v8h B1 = *(const v8h*)(lds + baseB[1] + bo + cq * 32);
            v8h B2 = *(const v8h*)(lds + baseB[2] + bo + cq * 32);
            const uint4* wq = wp + (tap * 4 + cq) * 256;
            v8h A00 = *(const v8h*)(wq);        // ct0 hi
            v8h A01 = *(const v8h*)(wq + 64);   // ct0 lo
            v8h A10 = *(const v8h*)(wq + 128);  // ct1 hi
            v8h A11 = *(const v8h*)(wq + 192);  // ct1 lo
            acc[0][0][0] = __builtin_amdgcn_mfma_f32_32x32x16_f16(A00, B0, acc[0][0][0], 0, 0, 0);
            acc[0][0][1] = __builtin_amdgcn_mfma_f32_32x32x16_f16(A01, B0, acc[0][0][1], 0, 0, 0);
            acc[0][1][0] = __builtin_amdgcn_mfma_f32_32x32x16_f16(A10, B0, acc[0][1][0], 0, 0, 0);
            acc[0][1][1] = __builtin_amdgcn_mfma_f32_32x32x16_f16(A11, B0, acc[0][1][1], 0, 0, 0);
            acc[1][0][0] = __builtin_amdgcn_mfma_f32_32x32x16_f16(A00, B1, acc[1][0][0], 0, 0, 0);
            acc[1][0][1] = __builtin_amdgcn_mfma_f32_32x32x16_f16(A01, B1, acc[1][0][1], 0, 0, 0);
            acc[1][1][0] = __builtin_amdgcn_mfma_f32_32x32x16_f16(A10, B1, acc[1][1][0], 0, 0, 0);
            acc[1][1][1] = __builtin_amdgcn_mfma_f32_32x32x16_f16(A11, B1, acc[1][1][1], 0, 0, 0);
            acc[2][0][0] = __builtin_amdgcn_mfma_f32_32x32x16_f16(A00, B2, acc[2][0][0], 0, 0, 0);
            acc[2][0][1] = __builtin_amdgcn_mfma_f32_32x32x16_f16(A01, B2, acc[2][0][1], 0, 0, 0);
            acc[2][1][0] = __builtin_amdgcn_mfma_f32_32x32x16_f16(A10, B2, acc[2][1][0], 0, 0, 0);
            acc[2][1][1] = __builtin_amdgcn_mfma_f32_32x32x16_f16(A11, B2, acc[2][1][1], 0, 0, 0);
        }
    }

    // ---- epilogue: u = hi + lo/2048 (overlap m24..31 double-written, identical) ----
    const float invs = 1.0f / 2048.0f;
    if (t < NT) {
#pragma unroll
        for (int mt = 0; mt < 3; mt++) {
            int m = mtb[mt] + ml;
            float* base = u + ((size_t)(b * NT + t) * NM + m) * 64;
#pragma unroll
            for (int ct = 0; ct < 2; ct++) {
#pragma unroll
                for (int g = 0; g < 4; g++) {
                    int co = ct * 32 + 8 * g + 4 * hseg;
                    float4 val;
                    val.x = acc[mt][ct][0][4 * g + 0] + acc[mt][ct][1][4 * g + 0] * invs;
                    val.y = acc[mt][ct][0][4 * g + 1] + acc[mt][ct][1][4 * g + 1] * invs;
                    val.z = acc[mt][ct][0][4 * g + 2] + acc[mt][ct][1][4 * g + 2] * invs;
                    val.w = acc[mt][ct][0][4 * g + 3] + acc[mt][ct][1][4 * g + 3] * invs;
                    *(float4*)(base + co) = val;
                }
            }
        }
    }
}

// ---- LIF over T: u fp32 -> compact f16 spikes, unroll-8 ----
__global__ void lif_spikes(const float* __restrict__ u, half_t* __restrict__ s2) {
    int tid = blockIdx.x * 256 + threadIdx.x;   // 81920
    int b = tid / 2560;
    int cm = tid % 2560;
    const float* up = u + (size_t)b * NT * 2560 + cm;
    half_t* sp = s2 + (size_t)b * NT * 2560 + cm;
    float v = 0.f;
    const float TAUc = 10.0f / 7.0f;
    for (int tb = 0; tb < 128; tb += 8) {
        float uu[8];
#pragma unroll
        for (int k = 0; k < 8; k++) uu[k] = up[(size_t)(tb + k) * 2560];
#pragma unroll
        for (int k = 0; k < 8; k++) {
            v = v + (uu[k] - v) / TAUc;
            float s = (v >= 1.0f) ? 1.0f : 0.0f;
            sp[(size_t)(tb + k) * 2560] = (half_t)s;
            if (v >= 1.0f) v = 0.f;
        }
    }
    float uu = up[(size_t)128 * 2560];
    v = v + (uu - v) / TAUc;
    sp[(size_t)128 * 2560] = (half_t)((v >= 1.0f) ? 1.0f : 0.0f);
}

// ---- LIF3: spike counts only (mean commutes with FC), unroll-8 ----
__global__ void lif_sum(const float* __restrict__ u, float* __restrict__ hsum) {
    int tid = blockIdx.x * 256 + threadIdx.x;   // 81920
    int b = tid / 2560;
    int cm = tid % 2560;                         // = m*64 + co
    int m = cm >> 6;
    int co = cm & 63;
    const float* up = u + (size_t)b * NT * 2560 + cm;
    float v = 0.f, cnt = 0.f;
    const float TAUc = 10.0f / 7.0f;
    for (int tb = 0; tb < 128; tb += 8) {
        float uu[8];
#pragma unroll
        for (int k = 0; k < 8; k++) uu[k] = up[(size_t)(tb + k) * 2560];
#pragma unroll
        for (int k = 0; k < 8; k++) {
            v = v + (uu[k] - v) / TAUc;
            if (v >= 1.0f) { cnt += 1.0f; v = 0.f; }
        }
    }
    float uu = up[(size_t)128 * 2560];
    v = v + (uu - v) / TAUc;
    if (v >= 1.0f) cnt += 1.0f;
    hsum[b * 2560 + co * NM + m] = cnt;          // feature index = c*40 + m
}

// ---- FC on counts: y[b,k] = bf[k] + (sum_cm cnt*wf[k,cm]) / 129 ----
__global__ void fc_out(const float* __restrict__ hsum, const float* __restrict__ wf,
                       const float* __restrict__ bfv, float* __restrict__ out) {
    int b = blockIdx.x;
    int tid = threadIdx.x;
    float p[12];
#pragma unroll
    for (int k = 0; k < 12; k++) p[k] = 0.0f;
    for (int cm = tid; cm < NC * NM; cm += 256) {
        float h = hsum[b * NC * NM + cm];
#pragma unroll
        for (int k = 0; k < 12; k++) p[k] += h * wf[k * (NC * NM) + cm];
    }
    __shared__ float red[12][4];
    int lane = tid & 63, w = tid >> 6;
#pragma unroll
    for (int k = 0; k < 12; k++) {
        float s = p[k];
#pragma unroll
        for (int off = 32; off > 0; off >>= 1) s += __shfl_down(s, off, 64);
        if (lane == 0) red[k][w] = s;
    }
    __syncthreads();
    if (tid < 12) {
        float s = red[tid][0] + red[tid][1] + red[tid][2] + red[tid][3];
        out[b * 12 + tid] = bfv[tid] + s / 129.0f;
    }
}

extern "C" void kernel_launch(void* const* d_in, const int* in_sizes, int n_in,
                              void* d_out, int out_size, void* d_ws, size_t ws_size,
                              hipStream_t stream) {
    const float* x  = (const float*)d_in[0];
    const float* w1 = (const float*)d_in[1];
    const float* w2 = (const float*)d_in[2];
    const float* w3 = (const float*)d_in[3];
    const float* wf = (const float*)d_in[4];
    const float* bf = (const float*)d_in[5];
    float* out = (float*)d_out;

    char* ws = (char*)d_ws;
    half_t* s1  = (half_t*)ws;                      // 21,135,360 B
    half_t* s2  = (half_t*)(ws + 21135360);         // 21,135,360 B
    float*  u   = (float*)(ws + 42270720);          // 42,270,720 B
    uint4*  wf2 = (uint4*)(ws + 84541440);          // 196,608 B
    uint4*  wf3 = (uint4*)(ws + 84738048);          // 196,608 B
    float* hsum = (float*)(ws + 84934656);          // 327,680 B (end ~85.3 MB)

    constexpr int LDS2 = 11 * 46 * MSTR;            // 72,864 B
    constexpr int LDS3 = 11 * 58 * MSTR;            // 91,872 B
    static bool attr_set = false;
    if (!attr_set) {
        hipFuncSetAttribute((const void*)&convW<4, 6, 3, 3, 46, 4>,
                            hipFuncAttributeMaxDynamicSharedMemorySize, LDS2);
        hipFuncSetAttribute((const void*)&convW<16, 24, 9, 9, 58, 16>,
                            hipFuncAttributeMaxDynamicSharedMemorySize, LDS3);
        attr_set = true;
    }

    prep_wfrag<<<48, 256, 0, stream>>>(w2, wf2);
    prep_wfrag<<<48, 256, 0, stream>>>(w3, wf3);

    conv1_lif1<<<dim3(10, 32), 256, 0, stream>>>(x, w1, s1);

    convW<4, 6, 3, 3, 46, 4><<<dim3(17, 32), 256, LDS2, stream>>>(s1, wf2, u);
    lif_spikes<<<320, 256, 0, stream>>>(u, s2);

    convW<16, 24, 9, 9, 58, 16><<<dim3(17, 32), 256, LDS3, stream>>>(s2, wf3, u);
    lif_sum<<<320, 256, 0, stream>>>(u, hsum);

    fc_out<<<32, 256, 0, stream>>>(hsum, wf, bf, out);
}